// Round 10
// baseline (146.876 us; speedup 1.0000x reference)
//
#include <hip/hip_runtime.h>
#include <hip/hip_fp16.h>
#include <math.h>

#define NN 50000
#define NE 800000
#define NEG 0.2f

#define NPB 128            // partition blocks
#define CHK 6250           // NE / NPB
#define NBUK 98            // bucket = dst >> 9  (512 dst per bucket)
#define LCAP 10240         // per-bucket LDS capacity
#define GB 782             // node-tile blocks: ceil(NN/64)

typedef __attribute__((ext_vector_type(8))) short short8v;  // 8 bf16 (4 VGPRs)
typedef __attribute__((ext_vector_type(4))) float f32x4;    // MFMA C/D frag

__device__ __forceinline__ float lrelu(float x){ return x > 0.f ? x : NEG * x; }

__device__ __forceinline__ short bf16t(float x){ return (short)(__float_as_uint(x) >> 16); }
__device__ __forceinline__ float bf16tof(short s){
    return __uint_as_float(((unsigned)(unsigned short)s) << 16);
}

// ---------- MFMA linear body: H(fp16) = X@W^T + b, plus attention scalars ----------
__device__ __forceinline__ void lin_body(int blk, int tid,
                                         const float* __restrict__ X,
                                         const float* __restrict__ W,
                                         const float* __restrict__ b,
                                         const float* __restrict__ att,
                                         __half* __restrict__ Hh,
                                         float* __restrict__ ad,
                                         float* __restrict__ as_, int n){
    int lane = tid & 63, wid = tid >> 6;
    int nb = blk * 64 + wid * 16;
    if (nb >= n) return;
    int r0 = lane & 15, rg = lane >> 4;

    short8v a_hi[2], a_lo[2];
    int arow = nb + r0; if (arow >= n) arow = n - 1;
    const float* xp = X + (size_t)arow * 64 + rg * 8;
    #pragma unroll
    for (int ks = 0; ks < 2; ++ks){
        #pragma unroll
        for (int j = 0; j < 8; ++j){
            float v = xp[ks * 32 + j];
            short h = bf16t(v);
            a_hi[ks][j] = h;
            a_lo[ks][j] = bf16t(v - bf16tof(h));
        }
    }

    f32x4 acc[4] = {{0,0,0,0},{0,0,0,0},{0,0,0,0},{0,0,0,0}};
    #pragma unroll
    for (int nt = 0; nt < 4; ++nt){
        const float* wp = W + (size_t)(nt * 16 + r0) * 64 + rg * 8;
        #pragma unroll
        for (int ks = 0; ks < 2; ++ks){
            short8v b_hi, b_lo;
            #pragma unroll
            for (int j = 0; j < 8; ++j){
                float v = wp[ks * 32 + j];
                short h = bf16t(v);
                b_hi[j] = h;
                b_lo[j] = bf16t(v - bf16tof(h));
            }
            acc[nt] = __builtin_amdgcn_mfma_f32_16x16x32_bf16(a_hi[ks], b_hi, acc[nt], 0, 0, 0);
            acc[nt] = __builtin_amdgcn_mfma_f32_16x16x32_bf16(a_hi[ks], b_lo, acc[nt], 0, 0, 0);
            acc[nt] = __builtin_amdgcn_mfma_f32_16x16x32_bf16(a_lo[ks], b_hi, acc[nt], 0, 0, 0);
        }
    }

    #pragma unroll
    for (int nt = 0; nt < 4; ++nt){
        float bb = b[nt * 16 + r0];
        #pragma unroll
        for (int q = 0; q < 4; ++q){
            int node = nb + rg * 4 + q;
            float v = acc[nt][q] + bb;
            acc[nt][q] = v;
            if (node < n) Hh[(size_t)node * 64 + nt * 16 + r0] = __float2half(v);
        }
    }

    float attd[4], atts[4];
    #pragma unroll
    for (int nt = 0; nt < 4; ++nt){
        attd[nt] = att[nt * 16 + r0];
        atts[nt] = att[64 + nt * 16 + r0];
    }
    #pragma unroll
    for (int q = 0; q < 4; ++q){
        float pd = 0.f, ps = 0.f;
        #pragma unroll
        for (int nt = 0; nt < 4; ++nt){
            pd = fmaf(attd[nt], acc[nt][q], pd);
            ps = fmaf(atts[nt], acc[nt][q], ps);
        }
        #pragma unroll
        for (int off = 8; off; off >>= 1){
            pd += __shfl_xor(pd, off);
            ps += __shfl_xor(ps, off);
        }
        int node = nb + rg * 4 + q;
        if (r0 == 0 && node < n){ ad[node] = pd; as_[node] = ps; }
    }
}

// ---------- fused front: lin1 [0,GB) | cntA [GB,GB+NPB) | wcomb [GB+NPB] ----------
__global__ __launch_bounds__(256) void k_fuse0(const float* __restrict__ X,
                                               const float* __restrict__ W1,
                                               const float* __restrict__ b1,
                                               const float* __restrict__ att1,
                                               __half* __restrict__ Hh,
                                               float* __restrict__ ad,
                                               float* __restrict__ as_,
                                               const int* __restrict__ dst,
                                               int* __restrict__ counts,
                                               const float* __restrict__ Wp1,
                                               const float* __restrict__ bp1,
                                               const float* __restrict__ Wp2,
                                               const float* __restrict__ bp2,
                                               float* __restrict__ Wc,
                                               float* __restrict__ bc){
    __shared__ int c[NBUK];
    int tid = threadIdx.x, blk = blockIdx.x;
    if (blk < GB){
        lin_body(blk, tid, X, W1, b1, att1, Hh, ad, as_, NN);
    } else if (blk < GB + NPB){
        int cb = blk - GB;
        for (int i = tid; i < NBUK; i += 256) c[i] = 0;
        __syncthreads();
        int beg = cb * CHK, end = min(beg + CHK, NE);
        for (int i = beg + tid; i < end; i += 256) atomicAdd(&c[dst[i] >> 9], 1);
        __syncthreads();
        for (int i = tid; i < NBUK; i += 256) counts[i * NPB + cb] = c[i];
    } else {
        for (int idx = tid; idx < 2560; idx += 256){
            int cc = idx >> 6, k = idx & 63;
            float s = 0.f;
            #pragma unroll 8
            for (int j = 0; j < 64; ++j) s = fmaf(Wp2[cc * 64 + j], Wp1[j * 64 + k], s);
            Wc[idx] = s;
        }
        if (tid < 40){
            float s = bp2[tid];
            for (int j = 0; j < 64; ++j) s = fmaf(Wp2[tid * 64 + j], bp1[j], s);
            bc[tid] = s;
        }
    }
}

// ---------- scan 1: per-bucket local exclusive scan ----------
__global__ __launch_bounds__(NPB) void k_scan1(int* __restrict__ counts,
                                               int* __restrict__ tot){
    __shared__ int wsum[2];
    int b = blockIdx.x, tid = threadIdx.x, lane = tid & 63, wid = tid >> 6;
    int v = counts[b * NPB + tid];
    int incl = v;
    #pragma unroll
    for (int off = 1; off < 64; off <<= 1){
        int t = __shfl_up(incl, off);
        if (lane >= off) incl += t;
    }
    if (lane == 63) wsum[wid] = incl;
    __syncthreads();
    int excl = incl - v + (wid ? wsum[0] : 0);
    counts[b * NPB + tid] = excl;
    if (tid == NPB - 1) tot[b] = excl + v;
}

// small in-block scan of tot[98] -> bb (exclusive)
__device__ __forceinline__ void bbase_scan(const int* __restrict__ tot,
                                           int* bb, int* wsum, int tid){
    int lane = tid & 63, w2 = tid >> 6;
    int vv = 0, incl = 0;
    if (tid < 128){
        vv = (tid < NBUK) ? tot[tid] : 0;
        incl = vv;
        #pragma unroll
        for (int off = 1; off < 64; off <<= 1){
            int t = __shfl_up(incl, off);
            if (lane >= off) incl += t;
        }
        if (lane == 63) wsum[w2] = incl;
    }
    __syncthreads();
    if (tid < NBUK) bb[tid] = incl - vv + (w2 ? wsum[0] : 0);
    __syncthreads();
}

// ---------- C: partition edges into private dense runs, packed u32 ----------
__global__ __launch_bounds__(256) void k_partC(const int* __restrict__ src,
                                               const int* __restrict__ dst,
                                               const int* __restrict__ cofs,
                                               const int* __restrict__ tot,
                                               unsigned* __restrict__ part){
    __shared__ int lcur[NBUK];
    __shared__ int bb[NBUK];
    __shared__ int wsum[2];
    int tid = threadIdx.x, blk = blockIdx.x;
    bbase_scan(tot, bb, wsum, tid);
    for (int i = tid; i < NBUK; i += 256) lcur[i] = bb[i] + cofs[i * NPB + blk];
    __syncthreads();
    int beg = blk * CHK, end = min(beg + CHK, NE);
    for (int i = beg + tid; i < end; i += 256){
        int d = dst[i];
        int pos = atomicAdd(&lcur[d >> 9], 1);
        part[pos] = ((unsigned)(d & 511) << 16) | (unsigned)src[i];
    }
}

// ---------- D: per-bucket CSR build; csr keeps packed (dloc<<16)|src ----------
__global__ __launch_bounds__(256) void k_buildD(const unsigned* __restrict__ part,
                                                const int* __restrict__ tot,
                                                int* __restrict__ rowstart,
                                                unsigned* __restrict__ csr){
    __shared__ int hist[512], cur[512];
    __shared__ unsigned csrbuf[LCAP];
    __shared__ int swave[4];
    __shared__ int bb[NBUK];
    __shared__ int wsum2[2];
    int tid = threadIdx.x, lane = tid & 63, wid = tid >> 6;
    int b = blockIdx.x;
    bbase_scan(tot, bb, wsum2, tid);
    int ebeg = bb[b], cnt = tot[b];

    for (int i = tid; i < 512; i += 256) hist[i] = 0;
    __syncthreads();
    for (int i = tid; i < cnt; i += 256) atomicAdd(&hist[part[ebeg + i] >> 16], 1);
    __syncthreads();

    int h0 = hist[2 * tid], h1 = hist[2 * tid + 1];
    int v = h0 + h1, incl = v;
    #pragma unroll
    for (int off = 1; off < 64; off <<= 1){
        int t = __shfl_up(incl, off);
        if (lane >= off) incl += t;
    }
    if (lane == 63) swave[wid] = incl;
    __syncthreads();
    int woff = 0;
    #pragma unroll
    for (int w = 0; w < 4; ++w) if (w < wid) woff += swave[w];
    int e0 = woff + incl - v;
    int e1 = e0 + h0;
    cur[2 * tid] = e0; cur[2 * tid + 1] = e1;
    int gi = b * 512 + 2 * tid;
    if (gi     <= NN) rowstart[gi]     = ebeg + e0;
    if (gi + 1 <= NN) rowstart[gi + 1] = ebeg + e1;
    __syncthreads();

    for (int i = tid; i < cnt; i += 256){
        unsigned u = part[ebeg + i];
        int lp = atomicAdd(&cur[u >> 16], 1);
        if (lp < LCAP) csrbuf[lp] = u;
    }
    __syncthreads();
    int m = min(cnt, LCAP);
    for (int i = tid; i < m; i += 256) csr[ebeg + i] = csrbuf[i];
}

// ---------- fused aggregation (16 nodes per wave, flat edges) -> LDS tile ----------
// gt tile: [16 nodes][68 floats] per wave. Returns with wave's tile filled.
__device__ __forceinline__ void agg_tile(const __half2* __restrict__ H2,
                                         const float* __restrict__ ad,
                                         const float* __restrict__ as_,
                                         const int* __restrict__ rowstart,
                                         const unsigned* __restrict__ csr,
                                         const float2* __restrict__ bias2,
                                         float (*e_sh)[64], unsigned (*s_sh)[64],
                                         float* gtw, int nb, int lane, int wid){
    int half = lane >> 5, hl = lane & 31;
    int bknode = nb & ~511;
    int ebeg = rowstart[nb], eend = rowstart[nb + 16];
    float2 bb = bias2[hl];

    float accx = 0.f, accy = 0.f, den = 0.f;
    int nrel = 0;
    int bn = ebeg, en = rowstart[nb + 1];

    for (int cb = ebeg; cb < eend && nrel < 16; cb += 64){
        int k = cb + lane;
        bool valid = k < eend;
        unsigned u = valid ? csr[k] : 0u;
        int s = (int)(u & 0xFFFFu);
        int nd = bknode + (int)(u >> 16);
        float e = valid ? __expf(lrelu(ad[nd] + as_[s])) : 0.f;
        e_sh[wid][lane] = e;
        s_sh[wid][lane] = (unsigned)s;
        int chunk_hi = min(cb + 64, eend);
        while (true){
            int hi = min(en, chunk_hi);
            int lo = max(bn, cb);
            for (int j = lo; j < hi; j += 16){
                #pragma unroll
                for (int t = 0; t < 8; ++t){
                    int it = j + 2 * t + half;
                    int tt = min(it - cb, 63);
                    float ee = e_sh[wid][tt];
                    int ss = (int)s_sh[wid][tt];
                    ee = (it < hi) ? ee : 0.f;
                    float2 f = __half22float2(H2[(size_t)ss * 32 + hl]);
                    accx = fmaf(ee, f.x, accx);
                    accy = fmaf(ee, f.y, accy);
                    den += ee;
                }
            }
            if (en <= chunk_hi){
                accx += __shfl_xor(accx, 32);
                accy += __shfl_xor(accy, 32);
                den  += __shfl_xor(den,  32);
                float inv = 1.f / (den + 1e-16f);
                gtw[nrel * 68 + 2 * hl]     = fmaxf(fmaf(accx, inv, bb.x), 0.f);
                gtw[nrel * 68 + 2 * hl + 1] = fmaxf(fmaf(accy, inv, bb.y), 0.f);
                accx = 0.f; accy = 0.f; den = 0.f;
                ++nrel;
                if (nrel == 16) break;
                bn = en; en = rowstart[nb + nrel + 1];
            } else break;
        }
    }
    // safety: flush any remaining (e.g. trailing zero-degree nodes)
    while (nrel < 16){
        gtw[nrel * 68 + 2 * hl]     = fmaxf(bb.x, 0.f);
        gtw[nrel * 68 + 2 * hl + 1] = fmaxf(bb.y, 0.f);
        ++nrel;
        if (nrel < 16){ bn = en; en = rowstart[nb + nrel + 1]; }
    }
}

// ---------- k_agglin: GAT-agg (layer L) + linear (layer L+1) fused ----------
__global__ __launch_bounds__(256) void k_agglin(const __half2* __restrict__ H2,
                                                const float* __restrict__ ad,
                                                const float* __restrict__ as_,
                                                const int* __restrict__ rowstart,
                                                const unsigned* __restrict__ csr,
                                                const float2* __restrict__ bias2,
                                                const float* __restrict__ W,
                                                const float* __restrict__ b,
                                                const float* __restrict__ att,
                                                __half* __restrict__ Hh,
                                                float* __restrict__ ad_o,
                                                float* __restrict__ as_o, int n){
    __shared__ float e_sh[4][64];
    __shared__ unsigned s_sh[4][64];
    __shared__ float gt[4][16 * 68];
    int tid = threadIdx.x, lane = tid & 63, wid = tid >> 6;
    int nb = blockIdx.x * 64 + wid * 16;
    if (nb >= n) return;

    agg_tile(H2, ad, as_, rowstart, csr, bias2, e_sh, s_sh, gt[wid], nb, lane, wid);

    // ---- MFMA linear phase (A from LDS tile) ----
    int r0 = lane & 15, rg = lane >> 4;
    short8v a_hi[2], a_lo[2];
    #pragma unroll
    for (int ks = 0; ks < 2; ++ks){
        #pragma unroll
        for (int j = 0; j < 8; ++j){
            float v = gt[wid][r0 * 68 + ks * 32 + rg * 8 + j];
            short h = bf16t(v);
            a_hi[ks][j] = h;
            a_lo[ks][j] = bf16t(v - bf16tof(h));
        }
    }

    f32x4 acc[4] = {{0,0,0,0},{0,0,0,0},{0,0,0,0},{0,0,0,0}};
    #pragma unroll
    for (int nt = 0; nt < 4; ++nt){
        const float* wp = W + (size_t)(nt * 16 + r0) * 64 + rg * 8;
        #pragma unroll
        for (int ks = 0; ks < 2; ++ks){
            short8v b_hi, b_lo;
            #pragma unroll
            for (int j = 0; j < 8; ++j){
                float v = wp[ks * 32 + j];
                short h = bf16t(v);
                b_hi[j] = h;
                b_lo[j] = bf16t(v - bf16tof(h));
            }
            acc[nt] = __builtin_amdgcn_mfma_f32_16x16x32_bf16(a_hi[ks], b_hi, acc[nt], 0, 0, 0);
            acc[nt] = __builtin_amdgcn_mfma_f32_16x16x32_bf16(a_hi[ks], b_lo, acc[nt], 0, 0, 0);
            acc[nt] = __builtin_amdgcn_mfma_f32_16x16x32_bf16(a_lo[ks], b_hi, acc[nt], 0, 0, 0);
        }
    }

    #pragma unroll
    for (int nt = 0; nt < 4; ++nt){
        float bbv = b[nt * 16 + r0];
        #pragma unroll
        for (int q = 0; q < 4; ++q){
            int node = nb + rg * 4 + q;
            float v = acc[nt][q] + bbv;
            acc[nt][q] = v;
            Hh[(size_t)node * 64 + nt * 16 + r0] = __float2half(v);
        }
    }

    float attd[4], atts[4];
    #pragma unroll
    for (int nt = 0; nt < 4; ++nt){
        attd[nt] = att[nt * 16 + r0];
        atts[nt] = att[64 + nt * 16 + r0];
    }
    #pragma unroll
    for (int q = 0; q < 4; ++q){
        float pd = 0.f, ps = 0.f;
        #pragma unroll
        for (int nt = 0; nt < 4; ++nt){
            pd = fmaf(attd[nt], acc[nt][q], pd);
            ps = fmaf(atts[nt], acc[nt][q], ps);
        }
        #pragma unroll
        for (int off = 8; off; off >>= 1){
            pd += __shfl_xor(pd, off);
            ps += __shfl_xor(ps, off);
        }
        int node = nb + rg * 4 + q;
        if (r0 == 0){ ad_o[node] = pd; as_o[node] = ps; }
    }
}

// ---------- k_aggmlp: GAT-agg (layer 2) + collapsed MLP + log_softmax ----------
__global__ __launch_bounds__(256) void k_aggmlp(const __half2* __restrict__ H2,
                                                const float* __restrict__ ad,
                                                const float* __restrict__ as_,
                                                const int* __restrict__ rowstart,
                                                const unsigned* __restrict__ csr,
                                                const float2* __restrict__ bias2,
                                                const float* __restrict__ Wc,
                                                const float* __restrict__ bc,
                                                float* __restrict__ out, int n){
    __shared__ float e_sh[4][64];
    __shared__ unsigned s_sh[4][64];
    __shared__ float gt[4][16 * 68];
    int tid = threadIdx.x, lane = tid & 63, wid = tid >> 6;
    int nb = blockIdx.x * 64 + wid * 16;
    if (nb >= n) return;

    agg_tile(H2, ad, as_, rowstart, csr, bias2, e_sh, s_sh, gt[wid], nb, lane, wid);

    int r0 = lane & 15, rg = lane >> 4;
    short8v a_hi[2], a_lo[2];
    #pragma unroll
    for (int ks = 0; ks < 2; ++ks){
        #pragma unroll
        for (int j = 0; j < 8; ++j){
            float v = gt[wid][r0 * 68 + ks * 32 + rg * 8 + j];
            short h = bf16t(v);
            a_hi[ks][j] = h;
            a_lo[ks][j] = bf16t(v - bf16tof(h));
        }
    }

    f32x4 acc[3] = {{0,0,0,0},{0,0,0,0},{0,0,0,0}};
    #pragma unroll
    for (int nt = 0; nt < 3; ++nt){
        int f = nt * 16 + r0;
        int fr = (f < 40) ? f : 39;
        const float* wp = Wc + (size_t)fr * 64 + rg * 8;
        #pragma unroll
        for (int ks = 0; ks < 2; ++ks){
            short8v b_hi, b_lo;
            #pragma unroll
            for (int j = 0; j < 8; ++j){
                float v = wp[ks * 32 + j];
                short h = bf16t(v);
                b_hi[j] = h;
                b_lo[j] = bf16t(v - bf16tof(h));
            }
            acc[nt] = __builtin_amdgcn_mfma_f32_16x16x32_bf16(a_hi[ks], b_hi, acc[nt], 0, 0, 0);
            acc[nt] = __builtin_amdgcn_mfma_f32_16x16x32_bf16(a_hi[ks], b_lo, acc[nt], 0, 0, 0);
            acc[nt] = __builtin_amdgcn_mfma_f32_16x16x32_bf16(a_lo[ks], b_hi, acc[nt], 0, 0, 0);
        }
    }

    float bcv[3];
    #pragma unroll
    for (int nt = 0; nt < 3; ++nt){
        int f = nt * 16 + r0;
        bcv[nt] = (f < 40) ? bc[f] : 0.f;
    }

    #pragma unroll
    for (int q = 0; q < 4; ++q){
        int node = nb + rg * 4 + q;
        float l0 = acc[0][q] + bcv[0];
        float l1 = acc[1][q] + bcv[1];
        float l2 = (32 + r0 < 40) ? acc[2][q] + bcv[2] : -INFINITY;
        float m = fmaxf(l0, fmaxf(l1, l2));
        #pragma unroll
        for (int off = 8; off; off >>= 1) m = fmaxf(m, __shfl_xor(m, off));
        float s = __expf(l0 - m) + __expf(l1 - m) + ((32 + r0 < 40) ? __expf(l2 - m) : 0.f);
        #pragma unroll
        for (int off = 8; off; off >>= 1) s += __shfl_xor(s, off);
        float lse = m + __logf(s);
        out[(size_t)node * 40 + r0]      = l0 - lse;
        out[(size_t)node * 40 + 16 + r0] = l1 - lse;
        if (32 + r0 < 40) out[(size_t)node * 40 + 32 + r0] = l2 - lse;
    }
}

extern "C" void kernel_launch(void* const* d_in, const int* in_sizes, int n_in,
                              void* d_out, int out_size, void* d_ws, size_t ws_size,
                              hipStream_t stream){
    const float* x     = (const float*)d_in[0];
    const int*   ei    = (const int*)  d_in[1];
    const float* W1    = (const float*)d_in[2];
    const float* b1    = (const float*)d_in[3];
    const float* att1  = (const float*)d_in[4];
    const float* bias1 = (const float*)d_in[5];
    const float* W2    = (const float*)d_in[6];
    const float* b2    = (const float*)d_in[7];
    const float* att2  = (const float*)d_in[8];
    const float* bias2 = (const float*)d_in[9];
    const float* Wp1   = (const float*)d_in[10];
    const float* bp1   = (const float*)d_in[11];
    const float* Wp2   = (const float*)d_in[12];
    const float* bp2   = (const float*)d_in[13];
    float* out = (float*)d_out;

    // workspace carve (float offsets; ~20.3 MB)
    float*    base     = (float*)d_ws;
    __half*   hhA      = (__half*)base;                 // NN*64 halves (1.6M f)
    __half*   hhB      = (__half*)(base + 1600000);     // NN*64 halves
    unsigned* part     = (unsigned*)(base + 3200000);   // 800,000
    unsigned* csr      = (unsigned*)(base + 4000000);   // 800,000
    int*      counts   = (int*)(base + 4800000);        // 12,544
    int*      tot      = (int*)(base + 4812944);        // 98 (+pad)
    int*      rowstart = (int*)(base + 4813072);        // 50,001 (+pad)
    float*    adA      = base + 4863080;                // 50,000
    float*    asA      = base + 4913080;                // 50,000
    float*    adB      = base + 4963080;                // 50,000
    float*    asB      = base + 5013080;                // 50,000
    float*    Wc       = base + 5063080;                // 2,560
    float*    bc       = base + 5065640;                // 40 (+pad)

    const int* srcv = ei;
    const int* dstv = ei + NE;

    k_fuse0 <<<GB + NPB + 1, 256, 0, stream>>>(x, W1, b1, att1, hhA, adA, asA,
                                               dstv, counts,
                                               Wp1, bp1, Wp2, bp2, Wc, bc);
    k_scan1 <<<NBUK, NPB, 0, stream>>>(counts, tot);
    k_partC <<<NPB, 256, 0, stream>>>(srcv, dstv, counts, tot, part);
    k_buildD<<<NBUK, 256, 0, stream>>>(part, tot, rowstart, csr);

    k_agglin<<<GB, 256, 0, stream>>>((const __half2*)hhA, adA, asA, rowstart, csr,
                                     (const float2*)bias1, W2, b2, att2,
                                     hhB, adB, asB, NN);
    k_aggmlp<<<GB, 256, 0, stream>>>((const __half2*)hhB, adB, asB, rowstart, csr,
                                     (const float2*)bias2, Wc, bc, out, NN);
}

// Round 11
// 140.841 us; speedup vs baseline: 1.0429x; 1.0429x over previous
//
#include <hip/hip_runtime.h>
#include <hip/hip_fp16.h>
#include <math.h>

#define NN 50000
#define NE 800000
#define NEG 0.2f

#define NPB 128            // partition blocks
#define CHK 6250           // NE / NPB
#define NBUK 98            // bucket = dst >> 9  (512 dst per bucket)
#define LCAP 10240         // per-bucket LDS capacity
#define GB 782             // lin blocks: ceil(NN/64)

typedef __attribute__((ext_vector_type(8))) short short8v;  // 8 bf16 (4 VGPRs)
typedef __attribute__((ext_vector_type(4))) float f32x4;    // MFMA C/D frag

__device__ __forceinline__ float lrelu(float x){ return x > 0.f ? x : NEG * x; }

__device__ __forceinline__ short bf16t(float x){ return (short)(__float_as_uint(x) >> 16); }
__device__ __forceinline__ float bf16tof(short s){
    return __uint_as_float(((unsigned)(unsigned short)s) << 16);
}

// ---------- MFMA linear body: H(fp16) = X@W^T + b, plus attention scalars ----------
__device__ __forceinline__ void lin_body(int blk, int tid,
                                         const float* __restrict__ X,
                                         const float* __restrict__ W,
                                         const float* __restrict__ b,
                                         const float* __restrict__ att,
                                         __half* __restrict__ Hh,
                                         float* __restrict__ ad,
                                         float* __restrict__ as_, int n){
    int lane = tid & 63, wid = tid >> 6;
    int nb = blk * 64 + wid * 16;
    if (nb >= n) return;
    int r0 = lane & 15, rg = lane >> 4;

    short8v a_hi[2], a_lo[2];
    int arow = nb + r0; if (arow >= n) arow = n - 1;
    const float* xp = X + (size_t)arow * 64 + rg * 8;
    #pragma unroll
    for (int ks = 0; ks < 2; ++ks){
        #pragma unroll
        for (int j = 0; j < 8; ++j){
            float v = xp[ks * 32 + j];
            short h = bf16t(v);
            a_hi[ks][j] = h;
            a_lo[ks][j] = bf16t(v - bf16tof(h));
        }
    }

    f32x4 acc[4] = {{0,0,0,0},{0,0,0,0},{0,0,0,0},{0,0,0,0}};
    #pragma unroll
    for (int nt = 0; nt < 4; ++nt){
        const float* wp = W + (size_t)(nt * 16 + r0) * 64 + rg * 8;
        #pragma unroll
        for (int ks = 0; ks < 2; ++ks){
            short8v b_hi, b_lo;
            #pragma unroll
            for (int j = 0; j < 8; ++j){
                float v = wp[ks * 32 + j];
                short h = bf16t(v);
                b_hi[j] = h;
                b_lo[j] = bf16t(v - bf16tof(h));
            }
            acc[nt] = __builtin_amdgcn_mfma_f32_16x16x32_bf16(a_hi[ks], b_hi, acc[nt], 0, 0, 0);
            acc[nt] = __builtin_amdgcn_mfma_f32_16x16x32_bf16(a_hi[ks], b_lo, acc[nt], 0, 0, 0);
            acc[nt] = __builtin_amdgcn_mfma_f32_16x16x32_bf16(a_lo[ks], b_hi, acc[nt], 0, 0, 0);
        }
    }

    #pragma unroll
    for (int nt = 0; nt < 4; ++nt){
        float bb = b[nt * 16 + r0];
        #pragma unroll
        for (int q = 0; q < 4; ++q){
            int node = nb + rg * 4 + q;
            float v = acc[nt][q] + bb;
            acc[nt][q] = v;
            if (node < n) Hh[(size_t)node * 64 + nt * 16 + r0] = __float2half(v);
        }
    }

    float attd[4], atts[4];
    #pragma unroll
    for (int nt = 0; nt < 4; ++nt){
        attd[nt] = att[nt * 16 + r0];
        atts[nt] = att[64 + nt * 16 + r0];
    }
    #pragma unroll
    for (int q = 0; q < 4; ++q){
        float pd = 0.f, ps = 0.f;
        #pragma unroll
        for (int nt = 0; nt < 4; ++nt){
            pd = fmaf(attd[nt], acc[nt][q], pd);
            ps = fmaf(atts[nt], acc[nt][q], ps);
        }
        #pragma unroll
        for (int off = 8; off; off >>= 1){
            pd += __shfl_xor(pd, off);
            ps += __shfl_xor(ps, off);
        }
        int node = nb + rg * 4 + q;
        if (r0 == 0 && node < n){ ad[node] = pd; as_[node] = ps; }
    }
}

// ---------- fused front: lin1 [0,GB) | cntA [GB,GB+NPB) | wcomb [GB+NPB] ----------
__global__ __launch_bounds__(256) void k_fuse0(const float* __restrict__ X,
                                               const float* __restrict__ W1,
                                               const float* __restrict__ b1,
                                               const float* __restrict__ att1,
                                               __half* __restrict__ Hh,
                                               float* __restrict__ ad,
                                               float* __restrict__ as_,
                                               const int* __restrict__ dst,
                                               int* __restrict__ counts,
                                               const float* __restrict__ Wp1,
                                               const float* __restrict__ bp1,
                                               const float* __restrict__ Wp2,
                                               const float* __restrict__ bp2,
                                               float* __restrict__ Wc,
                                               float* __restrict__ bc){
    __shared__ int c[NBUK];
    int tid = threadIdx.x, blk = blockIdx.x;
    if (blk < GB){
        lin_body(blk, tid, X, W1, b1, att1, Hh, ad, as_, NN);
    } else if (blk < GB + NPB){
        int cb = blk - GB;
        for (int i = tid; i < NBUK; i += 256) c[i] = 0;
        __syncthreads();
        int beg = cb * CHK, end = min(beg + CHK, NE);
        for (int i = beg + tid; i < end; i += 256) atomicAdd(&c[dst[i] >> 9], 1);
        __syncthreads();
        for (int i = tid; i < NBUK; i += 256) counts[i * NPB + cb] = c[i];
    } else {
        for (int idx = tid; idx < 2560; idx += 256){
            int cc = idx >> 6, k = idx & 63;
            float s = 0.f;
            #pragma unroll 8
            for (int j = 0; j < 64; ++j) s = fmaf(Wp2[cc * 64 + j], Wp1[j * 64 + k], s);
            Wc[idx] = s;
        }
        if (tid < 40){
            float s = bp2[tid];
            for (int j = 0; j < 64; ++j) s = fmaf(Wp2[tid * 64 + j], bp1[j], s);
            bc[tid] = s;
        }
    }
}

// small in-block scan of totsh[98] -> bb (exclusive); threads 0..127 participate
__device__ __forceinline__ void bbase_scan(const int* tot, int* bb, int* wsum, int tid){
    int lane = tid & 63, w2 = tid >> 6;
    int vv = 0, incl = 0;
    if (tid < 128){
        vv = (tid < NBUK) ? tot[tid] : 0;
        incl = vv;
        #pragma unroll
        for (int off = 1; off < 64; off <<= 1){
            int t = __shfl_up(incl, off);
            if (lane >= off) incl += t;
        }
        if (lane == 63) wsum[w2] = incl;
    }
    __syncthreads();
    if (tid < NBUK) bb[tid] = incl - vv + (w2 ? wsum[0] : 0);
    __syncthreads();
}

// ---------- C: partition; per-block offsets computed in-block from raw counts ----------
__global__ __launch_bounds__(256) void k_partC(const int* __restrict__ src,
                                               const int* __restrict__ dst,
                                               const int* __restrict__ counts,
                                               unsigned* __restrict__ part){
    __shared__ int lcur[NBUK];
    __shared__ int totsh[NBUK];
    __shared__ int bb[NBUK];
    __shared__ int wsum[2];
    int tid = threadIdx.x, blk = blockIdx.x;
    if (tid < NBUK){
        const int* row = counts + tid * NPB;
        int pre = 0, tt = 0;
        for (int i = 0; i < NPB; ++i){
            int cc = row[i];
            tt += cc;
            pre += (i < blk) ? cc : 0;
        }
        totsh[tid] = tt;
        lcur[tid] = pre;
    }
    __syncthreads();
    bbase_scan(totsh, bb, wsum, tid);
    if (tid < NBUK) lcur[tid] += bb[tid];
    __syncthreads();
    int beg = blk * CHK, end = min(beg + CHK, NE);
    for (int i = beg + tid; i < end; i += 256){
        int d = dst[i];
        int pos = atomicAdd(&lcur[d >> 9], 1);
        part[pos] = ((unsigned)(d & 511) << 16) | (unsigned)src[i];
    }
}

// ---------- D: per-bucket CSR build; bases recomputed in-block ----------
__global__ __launch_bounds__(256) void k_buildD(const unsigned* __restrict__ part,
                                                const int* __restrict__ counts,
                                                int* __restrict__ rowstart,
                                                int* __restrict__ csr){
    __shared__ int hist[512], cur[512];
    __shared__ int csrbuf[LCAP];
    __shared__ int swave[4];
    __shared__ int totsh[NBUK];
    __shared__ int bb[NBUK];
    __shared__ int wsum2[2];
    int tid = threadIdx.x, lane = tid & 63, wid = tid >> 6;
    int b = blockIdx.x;
    if (tid < NBUK){
        const int* row = counts + tid * NPB;
        int tt = 0;
        for (int i = 0; i < NPB; ++i) tt += row[i];
        totsh[tid] = tt;
    }
    __syncthreads();
    bbase_scan(totsh, bb, wsum2, tid);
    int ebeg = bb[b], cnt = totsh[b];

    for (int i = tid; i < 512; i += 256) hist[i] = 0;
    __syncthreads();
    for (int i = tid; i < cnt; i += 256) atomicAdd(&hist[part[ebeg + i] >> 16], 1);
    __syncthreads();

    int h0 = hist[2 * tid], h1 = hist[2 * tid + 1];
    int v = h0 + h1, incl = v;
    #pragma unroll
    for (int off = 1; off < 64; off <<= 1){
        int t = __shfl_up(incl, off);
        if (lane >= off) incl += t;
    }
    if (lane == 63) swave[wid] = incl;
    __syncthreads();
    int woff = 0;
    #pragma unroll
    for (int w = 0; w < 4; ++w) if (w < wid) woff += swave[w];
    int e0 = woff + incl - v;
    int e1 = e0 + h0;
    cur[2 * tid] = e0; cur[2 * tid + 1] = e1;
    int gi = b * 512 + 2 * tid;
    if (gi     <= NN) rowstart[gi]     = ebeg + e0;
    if (gi + 1 <= NN) rowstart[gi + 1] = ebeg + e1;
    __syncthreads();

    for (int i = tid; i < cnt; i += 256){
        unsigned u = part[ebeg + i];
        int lp = atomicAdd(&cur[u >> 16], 1);
        if (lp < LCAP) csrbuf[lp] = (int)(u & 0xFFFFu);
    }
    __syncthreads();
    int m = min(cnt, LCAP);
    for (int i = tid; i < m; i += 256) csr[ebeg + i] = csrbuf[i];
}

// ---------- plain lin kernel (layer 2) ----------
__global__ __launch_bounds__(256) void k_lin_mfma(const float* __restrict__ X,
                                                  const float* __restrict__ W,
                                                  const float* __restrict__ b,
                                                  const float* __restrict__ att,
                                                  __half* __restrict__ Hh,
                                                  float* __restrict__ ad,
                                                  float* __restrict__ as_, int n){
    lin_body(blockIdx.x, threadIdx.x, X, W, b, att, Hh, ad, as_, n);
}

// ---------- GAT aggregation: one wave per node, LDS-staged s/e, 8-deep gathers ----------
__global__ __launch_bounds__(256) void k_agg(const __half2* __restrict__ H2,
                                             const float* __restrict__ ad,
                                             const float* __restrict__ as_,
                                             const int* __restrict__ rowstart,
                                             const int* __restrict__ csr,
                                             const float2* __restrict__ bias2,
                                             float2* __restrict__ OUT2, int n){
    __shared__ float e_sh[4][64];
    __shared__ int   s_sh[4][64];
    int tid = threadIdx.x, lane = tid & 63, wid = tid >> 6;
    int node = blockIdx.x * 4 + wid;
    if (node >= n) return;
    int beg = rowstart[node], end = rowstart[node + 1];
    float adn = ad[node];
    int half = lane >> 5, hl = lane & 31;

    float accx = 0.f, accy = 0.f, denom = 0.f;
    for (int cbeg = beg; cbeg < end; cbeg += 64){
        int k = cbeg + lane;
        bool valid = (k < end);
        int s = valid ? csr[k] : 0;
        float e = valid ? __expf(lrelu(adn + as_[s])) : 0.f;
        e_sh[wid][lane] = e;
        s_sh[wid][lane] = valid ? s : 0;
        float es = e;
        #pragma unroll
        for (int off = 32; off; off >>= 1) es += __shfl_xor(es, off);
        denom += es;
        int cnt = min(64, end - cbeg);
        // 16-edge batches: 8 independent gathers in flight per half-wave lane
        for (int j = 0; j < cnt; j += 16){
            float2 f[8]; float ee[8];
            #pragma unroll
            for (int t = 0; t < 8; ++t){
                int idx = j + 2 * t + half;            // <= 63 always
                int ss = s_sh[wid][idx];
                ee[t] = e_sh[wid][idx];                // 0 beyond cnt -> no-op fma
                f[t] = __half22float2(H2[(size_t)ss * 32 + hl]);
            }
            #pragma unroll
            for (int t = 0; t < 8; ++t){
                accx = fmaf(ee[t], f[t].x, accx);
                accy = fmaf(ee[t], f[t].y, accy);
            }
        }
    }
    accx += __shfl_xor(accx, 32);
    accy += __shfl_xor(accy, 32);
    if (half == 0){
        float2 bb = bias2[hl];
        float inv = 1.f / (denom + 1e-16f);
        float2 o;
        o.x = fmaxf(fmaf(accx, inv, bb.x), 0.f);
        o.y = fmaxf(fmaf(accy, inv, bb.y), 0.f);
        OUT2[(size_t)node * 32 + hl] = o;
    }
}

// ---------- MFMA MLP: out = log_softmax(G@Wc^T + bc) ----------
__global__ __launch_bounds__(256) void k_mlp_mfma(const float* __restrict__ G,
                                                  const float* __restrict__ Wc,
                                                  const float* __restrict__ bc,
                                                  float* __restrict__ out, int n){
    int lane = threadIdx.x & 63, wid = threadIdx.x >> 6;
    int nb = blockIdx.x * 64 + wid * 16;
    if (nb >= n) return;
    int r0 = lane & 15, rg = lane >> 4;

    short8v a_hi[2], a_lo[2];
    int arow = nb + r0; if (arow >= n) arow = n - 1;
    const float* gp = G + (size_t)arow * 64 + rg * 8;
    #pragma unroll
    for (int ks = 0; ks < 2; ++ks){
        #pragma unroll
        for (int j = 0; j < 8; ++j){
            float v = gp[ks * 32 + j];
            short h = bf16t(v);
            a_hi[ks][j] = h;
            a_lo[ks][j] = bf16t(v - bf16tof(h));
        }
    }

    f32x4 acc[3] = {{0,0,0,0},{0,0,0,0},{0,0,0,0}};
    #pragma unroll
    for (int nt = 0; nt < 3; ++nt){
        int f = nt * 16 + r0;
        int fr = (f < 40) ? f : 39;
        const float* wp = Wc + (size_t)fr * 64 + rg * 8;
        #pragma unroll
        for (int ks = 0; ks < 2; ++ks){
            short8v b_hi, b_lo;
            #pragma unroll
            for (int j = 0; j < 8; ++j){
                float v = wp[ks * 32 + j];
                short h = bf16t(v);
                b_hi[j] = h;
                b_lo[j] = bf16t(v - bf16tof(h));
            }
            acc[nt] = __builtin_amdgcn_mfma_f32_16x16x32_bf16(a_hi[ks], b_hi, acc[nt], 0, 0, 0);
            acc[nt] = __builtin_amdgcn_mfma_f32_16x16x32_bf16(a_hi[ks], b_lo, acc[nt], 0, 0, 0);
            acc[nt] = __builtin_amdgcn_mfma_f32_16x16x32_bf16(a_lo[ks], b_hi, acc[nt], 0, 0, 0);
        }
    }

    float bcv[3];
    #pragma unroll
    for (int nt = 0; nt < 3; ++nt){
        int f = nt * 16 + r0;
        bcv[nt] = (f < 40) ? bc[f] : 0.f;
    }

    #pragma unroll
    for (int q = 0; q < 4; ++q){
        int node = nb + rg * 4 + q;
        float l0 = acc[0][q] + bcv[0];
        float l1 = acc[1][q] + bcv[1];
        float l2 = (32 + r0 < 40) ? acc[2][q] + bcv[2] : -INFINITY;
        float m = fmaxf(l0, fmaxf(l1, l2));
        #pragma unroll
        for (int off = 8; off; off >>= 1) m = fmaxf(m, __shfl_xor(m, off));
        float s = __expf(l0 - m) + __expf(l1 - m) + ((32 + r0 < 40) ? __expf(l2 - m) : 0.f);
        #pragma unroll
        for (int off = 8; off; off >>= 1) s += __shfl_xor(s, off);
        float lse = m + __logf(s);
        if (node < n){
            out[(size_t)node * 40 + r0]      = l0 - lse;
            out[(size_t)node * 40 + 16 + r0] = l1 - lse;
            if (32 + r0 < 40) out[(size_t)node * 40 + 32 + r0] = l2 - lse;
        }
    }
}

extern "C" void kernel_launch(void* const* d_in, const int* in_sizes, int n_in,
                              void* d_out, int out_size, void* d_ws, size_t ws_size,
                              hipStream_t stream){
    const float* x     = (const float*)d_in[0];
    const int*   ei    = (const int*)  d_in[1];
    const float* W1    = (const float*)d_in[2];
    const float* b1    = (const float*)d_in[3];
    const float* att1  = (const float*)d_in[4];
    const float* bias1 = (const float*)d_in[5];
    const float* W2    = (const float*)d_in[6];
    const float* b2    = (const float*)d_in[7];
    const float* att2  = (const float*)d_in[8];
    const float* bias2 = (const float*)d_in[9];
    const float* Wp1   = (const float*)d_in[10];
    const float* bp1   = (const float*)d_in[11];
    const float* Wp2   = (const float*)d_in[12];
    const float* bp2   = (const float*)d_in[13];
    float* out = (float*)d_out;

    // workspace carve (float offsets; ~26.3 MB; 16B-aligned blocks)
    float*    base     = (float*)d_ws;
    float*    g        = base;                          // 3,200,000 f
    __half*   hh       = (__half*)(base + 3200000);     // NN*64 halves
    unsigned* part     = (unsigned*)(base + 4800000);   // 800,000
    int*      csr      = (int*)(base + 5600000);        // 800,000
    int*      counts   = (int*)(base + 6400000);        // 12,544 (NBUK*NPB)
    int*      rowstart = (int*)(base + 6413200);        // 50,001 (+pad)
    float*    ad       = base + 6463208;                // 50,000
    float*    as_      = base + 6513208;                // 50,000
    float*    Wc       = base + 6563208;                // 2,560
    float*    bc       = base + 6565768;                // 40 (+pad)

    const int* srcv = ei;
    const int* dstv = ei + NE;

    // fused front: lin1 | cntA | wcomb
    k_fuse0 <<<GB + NPB + 1, 256, 0, stream>>>(x, W1, b1, att1, hh, ad, as_,
                                               dstv, counts,
                                               Wp1, bp1, Wp2, bp2, Wc, bc);
    k_partC <<<NPB, 256, 0, stream>>>(srcv, dstv, counts, part);
    k_buildD<<<NBUK, 256, 0, stream>>>(part, counts, rowstart, csr);

    int nb = (NN + 3) / 4;     // 1 node per wave (k_agg)
    k_agg     <<<nb, 256, 0, stream>>>((const __half2*)hh, ad, as_, rowstart, csr,
                                       (const float2*)bias1, (float2*)g, NN);
    k_lin_mfma<<<GB, 256, 0, stream>>>(g, W2, b2, att2, hh, ad, as_, NN);
    k_agg     <<<nb, 256, 0, stream>>>((const __half2*)hh, ad, as_, rowstart, csr,
                                       (const float2*)bias2, (float2*)g, NN);
    k_mlp_mfma<<<GB, 256, 0, stream>>>(g, Wc, bc, out, NN);
}